// Round 8
// baseline (7554.538 us; speedup 1.0000x reference)
//
#include <hip/hip_runtime.h>

#define B 8
#define D 512
#define T 2048
#define K 8192
#define M (B*T)

typedef float f32x4 __attribute__((ext_vector_type(4)));
typedef short bf16x8 __attribute__((ext_vector_type(8)));
typedef unsigned short us8 __attribute__((ext_vector_type(8)));

#define CAP 64
#define WIN 1.6e-3f

// ws layout (bytes)
#define WS_X2    0                  // f32[M]      65536
#define WS_E2    65536              // f32[K]      32768
#define WS_CNT   98304              // i32[M]      65536
#define WS_IDS   163840             // i32[M]      65536
#define WS_OVFC  229376             // i32         256
#define WS_OVFL  229632             // i32[M]      65536
#define WS_BEST  295168             // u64[M]      131072
#define WS_LIST  426240             // u16[M*CAP]  2097152
#define WS_AX    2523392            // bf16[M*512] 16777216
#define WS_BE    19300608           // bf16[K*512] 8388608
#define WS_NEED  27689216

__device__ inline unsigned short f2bf(float f) {   // RNE f32->bf16
    unsigned int x = __float_as_uint(f);
    unsigned int r = x + 0x7fffu + ((x >> 16) & 1u);
    return (unsigned short)(r >> 16);
}

// order-preserving f32 -> u32 (no NaNs in data)
__device__ inline unsigned int f2ord(float f) {
    unsigned int u = __float_as_uint(f);
    return (u & 0x80000000u) ? ~u : (u | 0x80000000u);
}

__device__ inline void gload16(const void* g, void* l) {
    __builtin_amdgcn_global_load_lds(
        (const __attribute__((address_space(1))) unsigned int*)g,
        (__attribute__((address_space(3))) unsigned int*)l, 16, 0, 0);
}

// ---------------- init cnt=0, ovf_cnt=0 ----------------
__global__ __launch_bounds__(256)
void vq_init(int* __restrict__ cnt, int* __restrict__ ovfc) {
    int i = blockIdx.x * 256 + threadIdx.x;
    cnt[i] = 0;
    if (i == 0) *ovfc = 0;
}

// ---- x2[p]: numpy-pairwise f32 sum of squares (VALIDATED round 3) --------
__global__ __launch_bounds__(256)
void vq_x2_kernel(const float* __restrict__ lat, float* __restrict__ x2g) {
#pragma clang fp contract(off)
    int p = blockIdx.x * 256 + threadIdx.x;
    int b = p / T, t = p % T;
    const float* base = lat + (size_t)b * D * T + t;
    float blk[4];
#pragma unroll
    for (int q = 0; q < 4; q++) {
        float r[8];
#pragma unroll
        for (int j = 0; j < 8; j++) {
            float v = base[(size_t)(q * 128 + j) * T];
            r[j] = __fmul_rn(v, v);
        }
        for (int i = 8; i < 128; i += 8) {
#pragma unroll
            for (int j = 0; j < 8; j++) {
                float v = base[(size_t)(q * 128 + i + j) * T];
                r[j] = __fadd_rn(r[j], __fmul_rn(v, v));
            }
        }
        blk[q] = __fadd_rn(__fadd_rn(__fadd_rn(r[0], r[1]), __fadd_rn(r[2], r[3])),
                           __fadd_rn(__fadd_rn(r[4], r[5]), __fadd_rn(r[6], r[7])));
    }
    x2g[p] = __fadd_rn(__fadd_rn(blk[0], blk[1]), __fadd_rn(blk[2], blk[3]));
}

// ---- e2[k]: numpy-pairwise f32 sum of squares (VALIDATED round 3) --------
__global__ __launch_bounds__(256)
void vq_e2_kernel(const float* __restrict__ emb, float* __restrict__ e2g) {
#pragma clang fp contract(off)
    int k = blockIdx.x * 256 + threadIdx.x;
    const float* base = emb + (size_t)k * D;
    float blk[4];
#pragma unroll
    for (int q = 0; q < 4; q++) {
        float r[8];
#pragma unroll
        for (int j = 0; j < 8; j++) {
            float v = base[q * 128 + j];
            r[j] = __fmul_rn(v, v);
        }
        for (int i = 8; i < 128; i += 8) {
#pragma unroll
            for (int j = 0; j < 8; j++) {
                float v = base[q * 128 + i + j];
                r[j] = __fadd_rn(r[j], __fmul_rn(v, v));
            }
        }
        blk[q] = __fadd_rn(__fadd_rn(__fadd_rn(r[0], r[1]), __fadd_rn(r[2], r[3])),
                           __fadd_rn(__fadd_rn(r[4], r[5]), __fadd_rn(r[6], r[7])));
    }
    e2g[k] = __fadd_rn(__fadd_rn(blk[0], blk[1]), __fadd_rn(blk[2], blk[3]));
}

// ---- prep A: Ax[m][d] = bf16(latents[b][d][t]) (VALIDATED round 4) -------
__global__ __launch_bounds__(256)
void vq_prep_a(const float* __restrict__ lat, unsigned short* __restrict__ Ax) {
    __shared__ float xsl[64][65];
    const int tid = threadIdx.x;
    const int m0 = blockIdx.x * 64;
    const int b = m0 / T, t0 = m0 % T;
    const float* lp = lat + (size_t)b * D * T + t0;
    for (int d0 = 0; d0 < D; d0 += 64) {
        if (d0) __syncthreads();
#pragma unroll
        for (int i = 0; i < 16; i++) {
            int idx = tid + i * 256;
            int dd = idx >> 6, tt = idx & 63;
            xsl[dd][tt] = lp[(size_t)(d0 + dd) * T + tt];
        }
        __syncthreads();
        int tt = tid & 63, g = tid >> 6;
        us8 va, vb;
#pragma unroll
        for (int j = 0; j < 8; j++) va[j] = f2bf(xsl[g * 16 + j][tt]);
#pragma unroll
        for (int j = 0; j < 8; j++) vb[j] = f2bf(xsl[g * 16 + 8 + j][tt]);
        *(us8*)&Ax[(size_t)(m0 + tt) * 512 + d0 + g * 16] = va;
        *(us8*)&Ax[(size_t)(m0 + tt) * 512 + d0 + g * 16 + 8] = vb;
    }
}

// ---- prep B: Be[k][d] = bf16(emb[k][d]) (VALIDATED round 4) --------------
__global__ __launch_bounds__(256)
void vq_prep_b(const float* __restrict__ emb, unsigned short* __restrict__ Be) {
    size_t i = ((size_t)blockIdx.x * 256 + threadIdx.x) * 4;
    float4 v = *(const float4*)&emb[i];
    ushort4 o;
    o.x = f2bf(v.x); o.y = f2bf(v.y); o.z = f2bf(v.z); o.w = f2bf(v.w);
    *(ushort4*)&Be[i] = o;
}

// ---- GEMM (bf16 MFMA), SINGLE PASS: running-prefix-min flagging ----------
// Wave mapping 4x1: wave wid owns rows wid*32..+31, ALL 128 cols of a tile,
// so each output row's tile-min is wave-local (8-reg min + 4 shfl_xor).
// Flag cond: d2 < min(runmin, tilemin) + WIN  (sound: prefix-subset min
// pm satisfies d2_a(k*) <= pm + 2*delta, 2*delta < WIN; validated r4/r5).
// T2 swizzle per rule #21. Dbuf 2-phase prefetch pipeline (r7).
#define BMg 128
#define BNg 128
#define NCHUNK 2048
#define NSTEPS ((NCHUNK / BNg) * 8)   // 128 stage-steps per block

__global__ __launch_bounds__(256, 2)
void vq_gemm(const unsigned short* __restrict__ Ax,
             const unsigned short* __restrict__ Be,
             const float* __restrict__ e2g,
             int* __restrict__ cnt,
             unsigned short* __restrict__ list) {
    __shared__ unsigned short As[2][BMg * 64];   // 2 x 16 KB
    __shared__ unsigned short Bs[2][BNg * 64];   // 2 x 16 KB
    __shared__ float e2s[NCHUNK];                // 8 KB

    const int tid = threadIdx.x;
    const int lane = tid & 63;
    const int wid = tid >> 6;
    const int m0 = blockIdx.x * BMg;
    const int nc0 = blockIdx.y * NCHUNK;

    for (int i = tid; i < NCHUNK; i += 256) e2s[i] = e2g[nc0 + i];

    // staging addresses (pre-swizzled source, linear LDS dest)
    const int rbase = wid * 8 + (lane >> 3);
    const int cbyte = (((lane & 7) ^ (lane >> 3)) * 16);
    const char* gA = (const char*)Ax + (size_t)(m0 + rbase) * 1024 + cbyte;
    const char* gB = (const char*)Be + (size_t)(nc0 + rbase) * 1024 + cbyte;
    const int ldsoff = wid * 1024;

    // fragment read bases (4x1 mapping; row&7 == lane&7 still holds)
    const int rbyteA = (wid * 32 + (lane & 15)) * 128;
    const int rbyteB = ((lane & 15)) * 128;

    float runmin[2][4];
#pragma unroll
    for (int mi = 0; mi < 2; mi++)
#pragma unroll
        for (int r = 0; r < 4; r++) runmin[mi][r] = 3.4e38f;

    // prologue: stage step 0 into buffer 0
#pragma unroll
    for (int i = 0; i < 4; i++) {
        gload16(gA + (size_t)i * 32768, (char*)As[0] + ldsoff + i * 4096);
        gload16(gB + (size_t)i * 32768, (char*)Bs[0] + ldsoff + i * 4096);
    }
    __syncthreads();   // drains vmcnt -> buf0 valid; fences e2s init

    f32x4 acc[2][8];
    for (int s = 0; s < NSTEPS; s++) {
        const int cur = s & 1;
        const int nt = s >> 3, ks = s & 7;

        if (ks == 0) {
#pragma unroll
            for (int mi = 0; mi < 2; mi++)
#pragma unroll
                for (int ni = 0; ni < 8; ni++) acc[mi][ni] = (f32x4){0.f, 0.f, 0.f, 0.f};
        }

        // issue next step's staging into the other buffer (overlaps MFMA)
        if (s + 1 < NSTEPS) {
            const int nt2 = (s + 1) >> 3, ks2 = (s + 1) & 7;
            const char* ga = gA + (size_t)(ks2 * 128);
            const char* gb = gB + (size_t)(nt2 * 128) * 1024 + (size_t)(ks2 * 128);
            char* la = (char*)As[cur ^ 1] + ldsoff;
            char* lb = (char*)Bs[cur ^ 1] + ldsoff;
#pragma unroll
            for (int i = 0; i < 4; i++) {
                gload16(ga + (size_t)i * 32768, la + i * 4096);
                gload16(gb + (size_t)i * 32768, lb + i * 4096);
            }
        }

        __builtin_amdgcn_s_setprio(1);
#pragma unroll
        for (int kh = 0; kh < 2; kh++) {
            const int cb = ((((lane >> 4) + kh * 4) ^ (lane & 7)) * 16);
            bf16x8 af[2], bfr[8];
#pragma unroll
            for (int mi = 0; mi < 2; mi++)
                af[mi] = *(const bf16x8*)((const char*)As[cur] + rbyteA + mi * 2048 + cb);
#pragma unroll
            for (int ni = 0; ni < 8; ni++)
                bfr[ni] = *(const bf16x8*)((const char*)Bs[cur] + rbyteB + ni * 2048 + cb);
#pragma unroll
            for (int mi = 0; mi < 2; mi++)
#pragma unroll
                for (int ni = 0; ni < 8; ni++)
                    acc[mi][ni] = __builtin_amdgcn_mfma_f32_16x16x32_bf16(
                        af[mi], bfr[ni], acc[mi][ni], 0, 0, 0);
        }
        __builtin_amdgcn_s_setprio(0);

        if (ks == 7) {
            const int n0l = nt * BNg;
            // d2 = e2 - 2*dot
#pragma unroll
            for (int mi = 0; mi < 2; mi++)
#pragma unroll
                for (int ni = 0; ni < 8; ni++) {
                    float e2v = e2s[n0l + ni * 16 + (lane & 15)];
#pragma unroll
                    for (int r = 0; r < 4; r++)
                        acc[mi][ni][r] = e2v - 2.0f * acc[mi][ni][r];
                }
            // tile-local row min (8 regs + 4 shfl within the 16-lane group)
            float tm[2][4];
#pragma unroll
            for (int mi = 0; mi < 2; mi++)
#pragma unroll
                for (int r = 0; r < 4; r++) {
                    float v = acc[mi][0][r];
#pragma unroll
                    for (int ni = 1; ni < 8; ni++) v = fminf(v, acc[mi][ni][r]);
                    v = fminf(v, __shfl_xor(v, 1));
                    v = fminf(v, __shfl_xor(v, 2));
                    v = fminf(v, __shfl_xor(v, 4));
                    v = fminf(v, __shfl_xor(v, 8));
                    tm[mi][r] = v;
                }
            // flag vs min(prefix, tile) + WIN, then update prefix
#pragma unroll
            for (int mi = 0; mi < 2; mi++)
#pragma unroll
                for (int r = 0; r < 4; r++) {
                    float th = fminf(runmin[mi][r], tm[mi][r]) + WIN;
#pragma unroll
                    for (int ni = 0; ni < 8; ni++) {
                        if (acc[mi][ni][r] < th) {
                            int m = m0 + wid * 32 + mi * 16 + (lane >> 4) * 4 + r;
                            int kcode = nc0 + n0l + ni * 16 + (lane & 15);
                            int slot = atomicAdd(&cnt[m], 1);
                            if (slot < CAP) list[m * CAP + slot] = (unsigned short)kcode;
                        }
                    }
                    runmin[mi][r] = fminf(runmin[mi][r], tm[mi][r]);
                }
        }
        __syncthreads();
    }
}

// ---- exact numpy-replica rescore; overflow points -> ovf list ------------
__global__ __launch_bounds__(64)
void vq_rescore(const float* __restrict__ lat, const float* __restrict__ emb,
                const float* __restrict__ x2g, const float* __restrict__ e2g,
                const int* __restrict__ cnt, const unsigned short* __restrict__ list,
                int* __restrict__ ids, int* __restrict__ ovfc,
                int* __restrict__ ovfl, unsigned long long* __restrict__ best) {
#pragma clang fp contract(off)
    __shared__ float xr[D];
    const int m = blockIdx.x;
    const int c = cnt[m];
    if (c > CAP) {
        if (threadIdx.x == 0) {
            int s = atomicAdd(ovfc, 1);
            ovfl[s] = m;
            best[m] = ~0ull;
        }
        return;
    }
    const int b = m / T, t = m % T;
    for (int d = threadIdx.x; d < D; d += 64)
        xr[d] = lat[(size_t)b * D * T + (size_t)d * T + t];
    __syncthreads();
    float bestv = 3.4e38f;
    int bk = 0x7fffffff;
    if ((int)threadIdx.x < c) {
        int k = list[m * CAP + threadIdx.x];
        const float* er = emb + (size_t)k * D;
        float s = 0.f;
        for (int d = 0; d < D; d++)
            s = __fadd_rn(s, __fmul_rn(xr[d], er[d]));
        float tmp = __fsub_rn(x2g[m], __fadd_rn(s, s));
        bestv = __fadd_rn(tmp, e2g[k]);
        bk = k;
    }
#pragma unroll
    for (int off = 1; off < 64; off <<= 1) {
        float ov = __shfl_xor(bestv, off);
        int ok = __shfl_xor(bk, off);
        if (ov < bestv || (ov == bestv && ok < bk)) { bestv = ov; bk = ok; }
    }
    if (threadIdx.x == 0) ids[m] = (bk == 0x7fffffff) ? 0 : bk;
}

// ---- PARALLEL exact scan for overflow points (8 k-slices x blocks) -------
__global__ __launch_bounds__(256)
void vq_fallback_par(const float* __restrict__ lat, const float* __restrict__ emb,
                     const float* __restrict__ x2g, const float* __restrict__ e2g,
                     const int* __restrict__ ovfc, const int* __restrict__ ovfl,
                     unsigned long long* __restrict__ best) {
#pragma clang fp contract(off)
    __shared__ float xr[D];
    __shared__ unsigned long long wmin[4];
    const int n = *ovfc;
    const int ntask = n * 8;
    for (int task = blockIdx.x; task < ntask; task += gridDim.x) {
        const int m = ovfl[task >> 3];
        const int slice = task & 7;
        const int b = m / T, t = m % T;
        for (int d = threadIdx.x; d < D; d += 256)
            xr[d] = lat[(size_t)b * D * T + (size_t)d * T + t];
        __syncthreads();
        const float x2v = x2g[m];
        unsigned long long bl = ~0ull;
        for (int k = slice * 1024 + threadIdx.x; k < slice * 1024 + 1024; k += 256) {
            const float* er = emb + (size_t)k * D;
            float s = 0.f;
            for (int d = 0; d < D; d++)
                s = __fadd_rn(s, __fmul_rn(xr[d], er[d]));
            float tmp = __fsub_rn(x2v, __fadd_rn(s, s));
            float dist = __fadd_rn(tmp, e2g[k]);
            unsigned long long pk = ((unsigned long long)f2ord(dist) << 32) |
                                    (unsigned long long)(unsigned int)k;
            bl = (pk < bl) ? pk : bl;
        }
#pragma unroll
        for (int off = 1; off < 64; off <<= 1) {
            unsigned long long o = __shfl_xor(bl, off);
            bl = (o < bl) ? o : bl;
        }
        if ((threadIdx.x & 63) == 0) wmin[threadIdx.x >> 6] = bl;
        __syncthreads();
        if (threadIdx.x == 0) {
            unsigned long long v = wmin[0];
            for (int i = 1; i < 4; i++) v = (wmin[i] < v) ? wmin[i] : v;
            atomicMin(&best[m], v);
        }
        __syncthreads();
    }
}

// ---- finalize overflow ids from packed best ------------------------------
__global__ __launch_bounds__(256)
void vq_finalize(const int* __restrict__ ovfc, const int* __restrict__ ovfl,
                 const unsigned long long* __restrict__ best, int* __restrict__ ids) {
    const int n = *ovfc;
    for (int i = blockIdx.x * 256 + threadIdx.x; i < n; i += gridDim.x * 256) {
        int m = ovfl[i];
        ids[m] = (int)(best[m] & 0xFFFFFFFFull);
    }
}

// ---- gather + transpose (VALIDATED) --------------------------------------
__global__ __launch_bounds__(256)
void vq_gather(const float* __restrict__ emb, const int* __restrict__ ids,
               float* __restrict__ out) {
    __shared__ float gbuf[64][65];
    __shared__ int ids_s[64];
    const int tid = threadIdx.x;
    const int m0 = blockIdx.x * 64;
    const int b = m0 / T, t0 = m0 % T;
    if (tid < 64) ids_s[tid] = ids[m0 + tid];
    float* outb = out + (size_t)b * D * T + t0;
    for (int d0 = 0; d0 < D; d0 += 64) {
        __syncthreads();
#pragma unroll
        for (int i = 0; i < 16; i++) {
            int idx = tid + i * 256;
            int tt = idx >> 6, dd = idx & 63;
            gbuf[tt][dd] = emb[(size_t)ids_s[tt] * D + d0 + dd];
        }
        __syncthreads();
#pragma unroll
        for (int i = 0; i < 16; i++) {
            int idx = tid + i * 256;
            int dd = idx >> 6, tt = idx & 63;
            outb[(size_t)(d0 + dd) * T + tt] = gbuf[tt][dd];
        }
    }
}

// ================= round-3 validated fallback path (small ws) =============
#define TM 64
#define TN 128
#define TD 32
__global__ __launch_bounds__(256)
void vq_main_old(const float* __restrict__ latents, const float* __restrict__ emb,
                 const float* __restrict__ x2g, const float* __restrict__ e2g,
                 float* __restrict__ out) {
#pragma clang fp contract(off)
    __shared__ __align__(16) float xs[TD][TM];
    __shared__ __align__(16) float es[TD][TN + 4];
    __shared__ float e2s[TN];
    __shared__ float x2s[TM];
    __shared__ int ids_s[TM];
    __shared__ __align__(16) float gbuf[64][65];
    const int tid = threadIdx.x;
    const int tn = tid & 15;
    const int tm = tid >> 4;
    const int m0 = blockIdx.x * TM;
    const int b = m0 / T;
    const int t0 = m0 % T;
    const float* lat = latents + (size_t)b * D * T + t0;
    if (tid < TM) x2s[tid] = x2g[m0 + tid];
    float minv[4];
    int mini[4];
#pragma unroll
    for (int i = 0; i < 4; i++) { minv[i] = 3.4e38f; mini[i] = 0; }
    for (int k0 = 0; k0 < K; k0 += TN) {
        __syncthreads();
        if (tid < TN) e2s[tid] = e2g[k0 + tid];
        float s[4][8];
#pragma unroll
        for (int i = 0; i < 4; i++)
#pragma unroll
            for (int j = 0; j < 8; j++) s[i][j] = 0.0f;
        for (int d0 = 0; d0 < D; d0 += TD) {
            if (d0) __syncthreads();
#pragma unroll
            for (int i = 0; i < 8; i++) {
                int idx = tid + i * 256;
                int dd = idx >> 6, tt = idx & 63;
                xs[dd][tt] = lat[(size_t)(d0 + dd) * T + tt];
            }
#pragma unroll
            for (int i = 0; i < 16; i++) {
                int idx = tid + i * 256;
                int nn = idx >> 5, dd = idx & 31;
                es[dd][nn] = emb[(size_t)(k0 + nn) * D + d0 + dd];
            }
            __syncthreads();
#pragma unroll
            for (int d = 0; d < TD; d++) {
                float4 xr = *(const float4*)&xs[d][tm * 4];
                float4 ea = *(const float4*)&es[d][tn * 4];
                float4 eb = *(const float4*)&es[d][64 + tn * 4];
                float xv[4] = {xr.x, xr.y, xr.z, xr.w};
                float ev[8] = {ea.x, ea.y, ea.z, ea.w, eb.x, eb.y, eb.z, eb.w};
#pragma unroll
                for (int i = 0; i < 4; i++)
#pragma unroll
                    for (int j = 0; j < 8; j++)
                        s[i][j] = __fadd_rn(s[i][j], __fmul_rn(xv[i], ev[j]));
            }
        }
#pragma unroll
        for (int i = 0; i < 4; i++) {
            float x2v = x2s[tm * 4 + i];
#pragma unroll
            for (int j = 0; j < 8; j++) {
                int col = (j < 4) ? (tn * 4 + j) : (64 + tn * 4 + (j - 4));
                float s2 = __fadd_rn(s[i][j], s[i][j]);
                float tmp = __fsub_rn(x2v, s2);
                float dist = __fadd_rn(tmp, e2s[col]);
                int kk = k0 + col;
                if (dist < minv[i]) { minv[i] = dist; mini[i] = kk; }
            }
        }
    }
#pragma unroll
    for (int i = 0; i < 4; i++) {
        float v1 = minv[i];
        int i1 = mini[i];
#pragma unroll
        for (int off = 1; off < 16; off <<= 1) {
            float ov = __shfl_xor(v1, off);
            int oi = __shfl_xor(i1, off);
            if (ov < v1 || (ov == v1 && oi < i1)) { v1 = ov; i1 = oi; }
        }
        if (tn == 0) ids_s[tm * 4 + i] = i1;
    }
    __syncthreads();
    float* outb = out + (size_t)b * D * T + t0;
    for (int d0 = 0; d0 < D; d0 += 64) {
        if (d0) __syncthreads();
#pragma unroll
        for (int i = 0; i < 16; i++) {
            int idx = tid + i * 256;
            int tt = idx >> 6, dd = idx & 63;
            gbuf[tt][dd] = emb[(size_t)ids_s[tt] * D + d0 + dd];
        }
        __syncthreads();
#pragma unroll
        for (int i = 0; i < 16; i++) {
            int idx = tid + i * 256;
            int dd = idx >> 6, tt = idx & 63;
            outb[(size_t)(d0 + dd) * T + tt] = gbuf[tt][dd];
        }
    }
}

extern "C" void kernel_launch(void* const* d_in, const int* in_sizes, int n_in,
                              void* d_out, int out_size, void* d_ws, size_t ws_size,
                              hipStream_t stream) {
    const float* latents = (const float*)d_in[0];
    const float* emb     = (const float*)d_in[1];
    float* out = (float*)d_out;
    char* ws = (char*)d_ws;
    float* x2g = (float*)(ws + WS_X2);
    float* e2g = (float*)(ws + WS_E2);

    if (ws_size < (size_t)WS_NEED) {   // validated round-3 path
        hipLaunchKernelGGL(vq_x2_kernel, dim3(M / 256), dim3(256), 0, stream, latents, x2g);
        hipLaunchKernelGGL(vq_e2_kernel, dim3(K / 256), dim3(256), 0, stream, emb, e2g);
        hipLaunchKernelGGL(vq_main_old, dim3(M / TM), dim3(256), 0, stream,
                           latents, emb, x2g, e2g, out);
        return;
    }

    int* cnt = (int*)(ws + WS_CNT);
    int* ids = (int*)(ws + WS_IDS);
    int* ovfc = (int*)(ws + WS_OVFC);
    int* ovfl = (int*)(ws + WS_OVFL);
    unsigned long long* best = (unsigned long long*)(ws + WS_BEST);
    unsigned short* list = (unsigned short*)(ws + WS_LIST);
    unsigned short* Ax = (unsigned short*)(ws + WS_AX);
    unsigned short* Be = (unsigned short*)(ws + WS_BE);

    hipLaunchKernelGGL(vq_init, dim3(M / 256), dim3(256), 0, stream, cnt, ovfc);
    hipLaunchKernelGGL(vq_x2_kernel, dim3(M / 256), dim3(256), 0, stream, latents, x2g);
    hipLaunchKernelGGL(vq_e2_kernel, dim3(K / 256), dim3(256), 0, stream, emb, e2g);
    hipLaunchKernelGGL(vq_prep_a, dim3(M / 64), dim3(256), 0, stream, latents, Ax);
    hipLaunchKernelGGL(vq_prep_b, dim3((K * D) / 1024), dim3(256), 0, stream, emb, Be);
    hipLaunchKernelGGL(vq_gemm, dim3(M / BMg, K / NCHUNK), dim3(256), 0, stream,
                       Ax, Be, e2g, cnt, list);
    hipLaunchKernelGGL(vq_rescore, dim3(M), dim3(64), 0, stream,
                       latents, emb, x2g, e2g, cnt, list, ids, ovfc, ovfl, best);
    hipLaunchKernelGGL(vq_fallback_par, dim3(2048), dim3(256), 0, stream,
                       latents, emb, x2g, e2g, ovfc, ovfl, best);
    hipLaunchKernelGGL(vq_finalize, dim3(64), dim3(256), 0, stream,
                       ovfc, ovfl, best, ids);
    hipLaunchKernelGGL(vq_gather, dim3(M / 64), dim3(256), 0, stream, emb, ids, out);
}

// Round 9
// 566.696 us; speedup vs baseline: 13.3309x; 13.3309x over previous
//
#include <hip/hip_runtime.h>

#define B 8
#define D 512
#define T 2048
#define K 8192
#define M (B*T)

typedef float f32x4 __attribute__((ext_vector_type(4)));
typedef short bf16x8 __attribute__((ext_vector_type(8)));
typedef unsigned short us8 __attribute__((ext_vector_type(8)));

#define CAP 192
#define WIN 1.6e-3f

// ws layout (bytes)
#define WS_X2    0                  // f32[M]      65536
#define WS_E2    65536              // f32[K]      32768
#define WS_CNT   98304              // i32[M]      65536
#define WS_IDS   163840             // i32[M]      65536
#define WS_OVFC  229376             // i32         256
#define WS_OVFL  229632             // i32[M]      65536
#define WS_BEST  295168             // u64[M]      131072
#define WS_GMIN  426240             // u32[M]      65536
#define WS_LIST  491776             // u16[M*CAP]  6291456
#define WS_AX    6783232            // bf16[M*512] 16777216
#define WS_BE    23560448           // bf16[K*512] 8388608
#define WS_NEED  31949056

__device__ inline unsigned short f2bf(float f) {   // RNE f32->bf16
    unsigned int x = __float_as_uint(f);
    unsigned int r = x + 0x7fffu + ((x >> 16) & 1u);
    return (unsigned short)(r >> 16);
}

// order-preserving f32 <-> u32 (no NaNs in data)
__device__ inline unsigned int f2ord(float f) {
    unsigned int u = __float_as_uint(f);
    return (u & 0x80000000u) ? ~u : (u | 0x80000000u);
}
__device__ inline float ord2f(unsigned int u) {
    return __uint_as_float((u & 0x80000000u) ? (u & 0x7fffffffu) : ~u);
}

__device__ inline void gload16(const void* g, void* l) {
    __builtin_amdgcn_global_load_lds(
        (const __attribute__((address_space(1))) unsigned int*)g,
        (__attribute__((address_space(3))) unsigned int*)l, 16, 0, 0);
}

// ---------------- init cnt=0, ovf_cnt=0, gmin=+inf(ord) ----------------
__global__ __launch_bounds__(256)
void vq_init(int* __restrict__ cnt, int* __restrict__ ovfc,
             unsigned int* __restrict__ gmin) {
    int i = blockIdx.x * 256 + threadIdx.x;
    cnt[i] = 0;
    gmin[i] = 0xFFFFFFFFu;
    if (i == 0) *ovfc = 0;
}

// ---- x2[p]: numpy-pairwise f32 sum of squares (VALIDATED round 3) --------
__global__ __launch_bounds__(256)
void vq_x2_kernel(const float* __restrict__ lat, float* __restrict__ x2g) {
#pragma clang fp contract(off)
    int p = blockIdx.x * 256 + threadIdx.x;
    int b = p / T, t = p % T;
    const float* base = lat + (size_t)b * D * T + t;
    float blk[4];
#pragma unroll
    for (int q = 0; q < 4; q++) {
        float r[8];
#pragma unroll
        for (int j = 0; j < 8; j++) {
            float v = base[(size_t)(q * 128 + j) * T];
            r[j] = __fmul_rn(v, v);
        }
        for (int i = 8; i < 128; i += 8) {
#pragma unroll
            for (int j = 0; j < 8; j++) {
                float v = base[(size_t)(q * 128 + i + j) * T];
                r[j] = __fadd_rn(r[j], __fmul_rn(v, v));
            }
        }
        blk[q] = __fadd_rn(__fadd_rn(__fadd_rn(r[0], r[1]), __fadd_rn(r[2], r[3])),
                           __fadd_rn(__fadd_rn(r[4], r[5]), __fadd_rn(r[6], r[7])));
    }
    x2g[p] = __fadd_rn(__fadd_rn(blk[0], blk[1]), __fadd_rn(blk[2], blk[3]));
}

// ---- e2[k]: numpy-pairwise f32 sum of squares (VALIDATED round 3) --------
__global__ __launch_bounds__(256)
void vq_e2_kernel(const float* __restrict__ emb, float* __restrict__ e2g) {
#pragma clang fp contract(off)
    int k = blockIdx.x * 256 + threadIdx.x;
    const float* base = emb + (size_t)k * D;
    float blk[4];
#pragma unroll
    for (int q = 0; q < 4; q++) {
        float r[8];
#pragma unroll
        for (int j = 0; j < 8; j++) {
            float v = base[q * 128 + j];
            r[j] = __fmul_rn(v, v);
        }
        for (int i = 8; i < 128; i += 8) {
#pragma unroll
            for (int j = 0; j < 8; j++) {
                float v = base[q * 128 + i + j];
                r[j] = __fadd_rn(r[j], __fmul_rn(v, v));
            }
        }
        blk[q] = __fadd_rn(__fadd_rn(__fadd_rn(r[0], r[1]), __fadd_rn(r[2], r[3])),
                           __fadd_rn(__fadd_rn(r[4], r[5]), __fadd_rn(r[6], r[7])));
    }
    e2g[k] = __fadd_rn(__fadd_rn(blk[0], blk[1]), __fadd_rn(blk[2], blk[3]));
}

// ---- prep A: Ax[m][d] = bf16(latents[b][d][t]) (VALIDATED round 4) -------
__global__ __launch_bounds__(256)
void vq_prep_a(const float* __restrict__ lat, unsigned short* __restrict__ Ax) {
    __shared__ float xsl[64][65];
    const int tid = threadIdx.x;
    const int m0 = blockIdx.x * 64;
    const int b = m0 / T, t0 = m0 % T;
    const float* lp = lat + (size_t)b * D * T + t0;
    for (int d0 = 0; d0 < D; d0 += 64) {
        if (d0) __syncthreads();
#pragma unroll
        for (int i = 0; i < 16; i++) {
            int idx = tid + i * 256;
            int dd = idx >> 6, tt = idx & 63;
            xsl[dd][tt] = lp[(size_t)(d0 + dd) * T + tt];
        }
        __syncthreads();
        int tt = tid & 63, g = tid >> 6;
        us8 va, vb;
#pragma unroll
        for (int j = 0; j < 8; j++) va[j] = f2bf(xsl[g * 16 + j][tt]);
#pragma unroll
        for (int j = 0; j < 8; j++) vb[j] = f2bf(xsl[g * 16 + 8 + j][tt]);
        *(us8*)&Ax[(size_t)(m0 + tt) * 512 + d0 + g * 16] = va;
        *(us8*)&Ax[(size_t)(m0 + tt) * 512 + d0 + g * 16 + 8] = vb;
    }
}

// ---- prep B: Be[k][d] = bf16(emb[k][d]) (VALIDATED round 4) --------------
__global__ __launch_bounds__(256)
void vq_prep_b(const float* __restrict__ emb, unsigned short* __restrict__ Be) {
    size_t i = ((size_t)blockIdx.x * 256 + threadIdx.x) * 4;
    float4 v = *(const float4*)&emb[i];
    ushort4 o;
    o.x = f2bf(v.x); o.y = f2bf(v.y); o.z = f2bf(v.z); o.w = f2bf(v.w);
    *(ushort4*)&Be[i] = o;
}

// ---- GEMM (bf16 MFMA), single pass, RACY-SHARED global-min flagging ------
// Per tile: wave-local row tile-min (4x1 wave mapping) -> atomicMin into
// gmin[m]; returned old value gives the freshest cross-block prefix min.
// Flag cond: d2 < min(old, tilemin) + WIN. Sound for ANY subset-min pm:
// d2_a(k*) <= pm + 2*delta < pm + WIN (r4/r5-validated bound), so the true
// argmin is always collected; rescore over the superset is exact ->
// d_out deterministic regardless of race timing.
// T2 swizzle per rule #21; dbuf 2-phase prefetch pipeline (r7).
#define BMg 128
#define BNg 128
#define NCHUNK 2048
#define NSTEPS ((NCHUNK / BNg) * 8)

__global__ __launch_bounds__(256, 2)
void vq_gemm(const unsigned short* __restrict__ Ax,
             const unsigned short* __restrict__ Be,
             const float* __restrict__ e2g,
             unsigned int* __restrict__ gmin,
             int* __restrict__ cnt,
             unsigned short* __restrict__ list) {
    __shared__ unsigned short As[2][BMg * 64];   // 2 x 16 KB
    __shared__ unsigned short Bs[2][BNg * 64];   // 2 x 16 KB
    __shared__ float e2s[NCHUNK];                // 8 KB

    const int tid = threadIdx.x;
    const int lane = tid & 63;
    const int wid = tid >> 6;
    const int m0 = blockIdx.x * BMg;
    const int nc0 = blockIdx.y * NCHUNK;

    for (int i = tid; i < NCHUNK; i += 256) e2s[i] = e2g[nc0 + i];

    // staging addresses (pre-swizzled source, linear LDS dest)
    const int rbase = wid * 8 + (lane >> 3);
    const int cbyte = (((lane & 7) ^ (lane >> 3)) * 16);
    const char* gA = (const char*)Ax + (size_t)(m0 + rbase) * 1024 + cbyte;
    const char* gB = (const char*)Be + (size_t)(nc0 + rbase) * 1024 + cbyte;
    const int ldsoff = wid * 1024;

    // fragment read bases (4x1 mapping; row&7 == lane&7 still holds)
    const int rbyteA = (wid * 32 + (lane & 15)) * 128;
    const int rbyteB = ((lane & 15)) * 128;

    // prologue: stage step 0 into buffer 0
#pragma unroll
    for (int i = 0; i < 4; i++) {
        gload16(gA + (size_t)i * 32768, (char*)As[0] + ldsoff + i * 4096);
        gload16(gB + (size_t)i * 32768, (char*)Bs[0] + ldsoff + i * 4096);
    }
    __syncthreads();   // drains vmcnt -> buf0 valid; fences e2s init

    f32x4 acc[2][8];
    for (int s = 0; s < NSTEPS; s++) {
        const int cur = s & 1;
        const int nt = s >> 3, ks = s & 7;

        if (ks == 0) {
#pragma unroll
            for (int mi = 0; mi < 2; mi++)
#pragma unroll
                for (int ni = 0; ni < 8; ni++) acc[mi][ni] = (f32x4){0.f, 0.f, 0.f, 0.f};
        }

        // issue next step's staging into the other buffer (overlaps MFMA)
        if (s + 1 < NSTEPS) {
            const int nt2 = (s + 1) >> 3, ks2 = (s + 1) & 7;
            const char* ga = gA + (size_t)(ks2 * 128);
            const char* gb = gB + (size_t)(nt2 * 128) * 1024 + (size_t)(ks2 * 128);
            char* la = (char*)As[cur ^ 1] + ldsoff;
            char* lb = (char*)Bs[cur ^ 1] + ldsoff;
#pragma unroll
            for (int i = 0; i < 4; i++) {
                gload16(ga + (size_t)i * 32768, la + i * 4096);
                gload16(gb + (size_t)i * 32768, lb + i * 4096);
            }
        }

        __builtin_amdgcn_s_setprio(1);
#pragma unroll
        for (int kh = 0; kh < 2; kh++) {
            const int cb = ((((lane >> 4) + kh * 4) ^ (lane & 7)) * 16);
            bf16x8 af[2], bfr[8];
#pragma unroll
            for (int mi = 0; mi < 2; mi++)
                af[mi] = *(const bf16x8*)((const char*)As[cur] + rbyteA + mi * 2048 + cb);
#pragma unroll
            for (int ni = 0; ni < 8; ni++)
                bfr[ni] = *(const bf16x8*)((const char*)Bs[cur] + rbyteB + ni * 2048 + cb);
#pragma unroll
            for (int mi = 0; mi < 2; mi++)
#pragma unroll
                for (int ni = 0; ni < 8; ni++)
                    acc[mi][ni] = __builtin_amdgcn_mfma_f32_16x16x32_bf16(
                        af[mi], bfr[ni], acc[mi][ni], 0, 0, 0);
        }
        __builtin_amdgcn_s_setprio(0);

        if (ks == 7) {
            const int n0l = nt * BNg;
            // d2 = e2 - 2*dot
#pragma unroll
            for (int mi = 0; mi < 2; mi++)
#pragma unroll
                for (int ni = 0; ni < 8; ni++) {
                    float e2v = e2s[n0l + ni * 16 + (lane & 15)];
#pragma unroll
                    for (int r = 0; r < 4; r++)
                        acc[mi][ni][r] = e2v - 2.0f * acc[mi][ni][r];
                }
            // per-row tile min (8 regs + 4 shfl within 16-lane group),
            // share via gmin atomicMin, flag vs freshest global prefix.
#pragma unroll
            for (int mi = 0; mi < 2; mi++)
#pragma unroll
                for (int r = 0; r < 4; r++) {
                    float v = acc[mi][0][r];
#pragma unroll
                    for (int ni = 1; ni < 8; ni++) v = fminf(v, acc[mi][ni][r]);
                    v = fminf(v, __shfl_xor(v, 1));
                    v = fminf(v, __shfl_xor(v, 2));
                    v = fminf(v, __shfl_xor(v, 4));
                    v = fminf(v, __shfl_xor(v, 8));
                    const int m = m0 + wid * 32 + mi * 16 + (lane >> 4) * 4 + r;
                    unsigned int to = f2ord(v);
                    unsigned int old = 0xFFFFFFFFu;
                    if ((lane & 15) == 0) old = atomicMin(&gmin[m], to);
                    old = __shfl(old, lane & 48);   // broadcast group leader
                    unsigned int curo = (old < to) ? old : to;
                    float th = ord2f(curo) + WIN;
#pragma unroll
                    for (int ni = 0; ni < 8; ni++) {
                        if (acc[mi][ni][r] < th) {
                            int kcode = nc0 + n0l + ni * 16 + (lane & 15);
                            int slot = atomicAdd(&cnt[m], 1);
                            if (slot < CAP) list[m * CAP + slot] = (unsigned short)kcode;
                        }
                    }
                }
        }
        __syncthreads();
    }
}

// ---- exact numpy-replica rescore (<=CAP cands, 64-thread rounds) ---------
__global__ __launch_bounds__(64)
void vq_rescore(const float* __restrict__ lat, const float* __restrict__ emb,
                const float* __restrict__ x2g, const float* __restrict__ e2g,
                const int* __restrict__ cnt, const unsigned short* __restrict__ list,
                int* __restrict__ ids, int* __restrict__ ovfc,
                int* __restrict__ ovfl, unsigned long long* __restrict__ best) {
#pragma clang fp contract(off)
    __shared__ float xr[D];
    const int m = blockIdx.x;
    const int c = cnt[m];
    if (c > CAP) {
        if (threadIdx.x == 0) {
            int s = atomicAdd(ovfc, 1);
            ovfl[s] = m;
            best[m] = ~0ull;
        }
        return;
    }
    const int b = m / T, t = m % T;
    for (int d = threadIdx.x; d < D; d += 64)
        xr[d] = lat[(size_t)b * D * T + (size_t)d * T + t];
    __syncthreads();
    const float x2v = x2g[m];
    float bestv = 3.4e38f;
    int bk = 0x7fffffff;
    for (int j = threadIdx.x; j < c; j += 64) {
        int k = list[m * CAP + j];
        const float* er = emb + (size_t)k * D;
        float s = 0.f;
        for (int d = 0; d < D; d++)
            s = __fadd_rn(s, __fmul_rn(xr[d], er[d]));
        float tmp = __fsub_rn(x2v, __fadd_rn(s, s));
        float dist = __fadd_rn(tmp, e2g[k]);
        if (dist < bestv || (dist == bestv && k < bk)) { bestv = dist; bk = k; }
    }
#pragma unroll
    for (int off = 1; off < 64; off <<= 1) {
        float ov = __shfl_xor(bestv, off);
        int ok = __shfl_xor(bk, off);
        if (ov < bestv || (ov == bestv && ok < bk)) { bestv = ov; bk = ok; }
    }
    if (threadIdx.x == 0) ids[m] = (bk == 0x7fffffff) ? 0 : bk;
}

// ---- PARALLEL exact scan for overflow points (8 k-slices x blocks) -------
__global__ __launch_bounds__(256)
void vq_fallback_par(const float* __restrict__ lat, const float* __restrict__ emb,
                     const float* __restrict__ x2g, const float* __restrict__ e2g,
                     const int* __restrict__ ovfc, const int* __restrict__ ovfl,
                     unsigned long long* __restrict__ best) {
#pragma clang fp contract(off)
    __shared__ float xr[D];
    __shared__ unsigned long long wmin[4];
    const int n = *ovfc;
    const int ntask = n * 8;
    for (int task = blockIdx.x; task < ntask; task += gridDim.x) {
        const int m = ovfl[task >> 3];
        const int slice = task & 7;
        const int b = m / T, t = m % T;
        for (int d = threadIdx.x; d < D; d += 256)
            xr[d] = lat[(size_t)b * D * T + (size_t)d * T + t];
        __syncthreads();
        const float x2v = x2g[m];
        unsigned long long bl = ~0ull;
        for (int k = slice * 1024 + threadIdx.x; k < slice * 1024 + 1024; k += 256) {
            const float* er = emb + (size_t)k * D;
            float s = 0.f;
            for (int d = 0; d < D; d++)
                s = __fadd_rn(s, __fmul_rn(xr[d], er[d]));
        float tmp = __fsub_rn(x2v, __fadd_rn(s, s));
            float dist = __fadd_rn(tmp, e2g[k]);
            unsigned long long pk = ((unsigned long long)f2ord(dist) << 32) |
                                    (unsigned long long)(unsigned int)k;
            bl = (pk < bl) ? pk : bl;
        }
#pragma unroll
        for (int off = 1; off < 64; off <<= 1) {
            unsigned long long o = __shfl_xor(bl, off);
            bl = (o < bl) ? o : bl;
        }
        if ((threadIdx.x & 63) == 0) wmin[threadIdx.x >> 6] = bl;
        __syncthreads();
        if (threadIdx.x == 0) {
            unsigned long long v = wmin[0];
            for (int i = 1; i < 4; i++) v = (wmin[i] < v) ? wmin[i] : v;
            atomicMin(&best[m], v);
        }
        __syncthreads();
    }
}

// ---- finalize overflow ids from packed best ------------------------------
__global__ __launch_bounds__(256)
void vq_finalize(const int* __restrict__ ovfc, const int* __restrict__ ovfl,
                 const unsigned long long* __restrict__ best, int* __restrict__ ids) {
    const int n = *ovfc;
    for (int i = blockIdx.x * 256 + threadIdx.x; i < n; i += gridDim.x * 256) {
        int m = ovfl[i];
        ids[m] = (int)(best[m] & 0xFFFFFFFFull);
    }
}

// ---- gather + transpose (VALIDATED) --------------------------------------
__global__ __launch_bounds__(256)
void vq_gather(const float* __restrict__ emb, const int* __restrict__ ids,
               float* __restrict__ out) {
    __shared__ float gbuf[64][65];
    __shared__ int ids_s[64];
    const int tid = threadIdx.x;
    const int m0 = blockIdx.x * 64;
    const int b = m0 / T, t0 = m0 % T;
    if (tid < 64) ids_s[tid] = ids[m0 + tid];
    float* outb = out + (size_t)b * D * T + t0;
    for (int d0 = 0; d0 < D; d0 += 64) {
        __syncthreads();
#pragma unroll
        for (int i = 0; i < 16; i++) {
            int idx = tid + i * 256;
            int tt = idx >> 6, dd = idx & 63;
            gbuf[tt][dd] = emb[(size_t)ids_s[tt] * D + d0 + dd];
        }
        __syncthreads();
#pragma unroll
        for (int i = 0; i < 16; i++) {
            int idx = tid + i * 256;
            int dd = idx >> 6, tt = idx & 63;
            outb[(size_t)(d0 + dd) * T + tt] = gbuf[tt][dd];
        }
    }
}

// ================= round-3 validated fallback path (small ws) =============
#define TM 64
#define TN 128
#define TD 32
__global__ __launch_bounds__(256)
void vq_main_old(const float* __restrict__ latents, const float* __restrict__ emb,
                 const float* __restrict__ x2g, const float* __restrict__ e2g,
                 float* __restrict__ out) {
#pragma clang fp contract(off)
    __shared__ __align__(16) float xs[TD][TM];
    __shared__ __align__(16) float es[TD][TN + 4];
    __shared__ float e2s[TN];
    __shared__ float x2s[TM];
    __shared__ int ids_s[TM];
    __shared__ __align__(16) float gbuf[64][65];
    const int tid = threadIdx.x;
    const int tn = tid & 15;
    const int tm = tid >> 4;
    const int m0 = blockIdx.x * TM;
    const int b = m0 / T;
    const int t0 = m0 % T;
    const float* lat = latents + (size_t)b * D * T + t0;
    if (tid < TM) x2s[tid] = x2g[m0 + tid];
    float minv[4];
    int mini[4];
#pragma unroll
    for (int i = 0; i < 4; i++) { minv[i] = 3.4e38f; mini[i] = 0; }
    for (int k0 = 0; k0 < K; k0 += TN) {
        __syncthreads();
        if (tid < TN) e2s[tid] = e2g[k0 + tid];
        float s[4][8];
#pragma unroll
        for (int i = 0; i < 4; i++)
#pragma unroll
            for (int j = 0; j < 8; j++) s[i][j] = 0.0f;
        for (int d0 = 0; d0 < D; d0 += TD) {
            if (d0) __syncthreads();
#pragma unroll
            for (int i = 0; i < 8; i++) {
                int idx = tid + i * 256;
                int dd = idx >> 6, tt = idx & 63;
                xs[dd][tt] = lat[(size_t)(d0 + dd) * T + tt];
            }
#pragma unroll
            for (int i = 0; i < 16; i++) {
                int idx = tid + i * 256;
                int nn = idx >> 5, dd = idx & 31;
                es[dd][nn] = emb[(size_t)(k0 + nn) * D + d0 + dd];
            }
            __syncthreads();
#pragma unroll
            for (int d = 0; d < TD; d++) {
                float4 xr = *(const float4*)&xs[d][tm * 4];
                float4 ea = *(const float4*)&es[d][tn * 4];
                float4 eb = *(const float4*)&es[d][64 + tn * 4];
                float xv[4] = {xr.x, xr.y, xr.z, xr.w};
                float ev[8] = {ea.x, ea.y, ea.z, ea.w, eb.x, eb.y, eb.z, eb.w};
#pragma unroll
                for (int i = 0; i < 4; i++)
#pragma unroll
                    for (int j = 0; j < 8; j++)
                        s[i][j] = __fadd_rn(s[i][j], __fmul_rn(xv[i], ev[j]));
            }
        }
#pragma unroll
        for (int i = 0; i < 4; i++) {
            float x2v = x2s[tm * 4 + i];
#pragma unroll
            for (int j = 0; j < 8; j++) {
                int col = (j < 4) ? (tn * 4 + j) : (64 + tn * 4 + (j - 4));
                float s2 = __fadd_rn(s[i][j], s[i][j]);
                float tmp = __fsub_rn(x2v, s2);
                float dist = __fadd_rn(tmp, e2s[col]);
                int kk = k0 + col;
                if (dist < minv[i]) { minv[i] = dist; mini[i] = kk; }
            }
        }
    }
#pragma unroll
    for (int i = 0; i < 4; i++) {
        float v1 = minv[i];
        int i1 = mini[i];
#pragma unroll
        for (int off = 1; off < 16; off <<= 1) {
            float ov = __shfl_xor(v1, off);
            int oi = __shfl_xor(i1, off);
            if (ov < v1 || (ov == v1 && oi < i1)) { v1 = ov; i1 = oi; }
        }
        if (tn == 0) ids_s[tm * 4 + i] = i1;
    }
    __syncthreads();
    float* outb = out + (size_t)b * D * T + t0;
    for (int d0 = 0; d0 < D; d0 += 64) {
        if (d0) __syncthreads();
#pragma unroll
        for (int i = 0; i < 16; i++) {
            int idx = tid + i * 256;
            int tt = idx >> 6, dd = idx & 63;
            gbuf[tt][dd] = emb[(size_t)ids_s[tt] * D + d0 + dd];
        }
        __syncthreads();
#pragma unroll
        for (int i = 0; i < 16; i++) {
            int idx = tid + i * 256;
            int dd = idx >> 6, tt = idx & 63;
            outb[(size_t)(d0 + dd) * T + tt] = gbuf[tt][dd];
        }
    }
}

extern "C" void kernel_launch(void* const* d_in, const int* in_sizes, int n_in,
                              void* d_out, int out_size, void* d_ws, size_t ws_size,
                              hipStream_t stream) {
    const float* latents = (const float*)d_in[0];
    const float* emb     = (const float*)d_in[1];
    float* out = (float*)d_out;
    char* ws = (char*)d_ws;
    float* x2g = (float*)(ws + WS_X2);
    float* e2g = (float*)(ws + WS_E2);

    if (ws_size < (size_t)WS_NEED) {   // validated round-3 path
        hipLaunchKernelGGL(vq_x2_kernel, dim3(M / 256), dim3(256), 0, stream, latents, x2g);
        hipLaunchKernelGGL(vq_e2_kernel, dim3(K / 256), dim3(256), 0, stream, emb, e2g);
        hipLaunchKernelGGL(vq_main_old, dim3(M / TM), dim3(256), 0, stream,
                           latents, emb, x2g, e2g, out);
        return;
    }

    int* cnt = (int*)(ws + WS_CNT);
    int* ids = (int*)(ws + WS_IDS);
    int* ovfc = (int*)(ws + WS_OVFC);
    int* ovfl = (int*)(ws + WS_OVFL);
    unsigned long long* best = (unsigned long long*)(ws + WS_BEST);
    unsigned int* gmin = (unsigned int*)(ws + WS_GMIN);
    unsigned short* list = (unsigned short*)(ws + WS_LIST);
    unsigned short* Ax = (unsigned short*)(ws + WS_AX);
    unsigned short* Be = (unsigned short*)(ws + WS_BE);

    hipLaunchKernelGGL(vq_init, dim3(M / 256), dim3(256), 0, stream, cnt, ovfc, gmin);
    hipLaunchKernelGGL(vq_x2_kernel, dim3(M / 256), dim3(256), 0, stream, latents, x2g);
    hipLaunchKernelGGL(vq_e2_kernel, dim3(K / 256), dim3(256), 0, stream, emb, e2g);
    hipLaunchKernelGGL(vq_prep_a, dim3(M / 64), dim3(256), 0, stream, latents, Ax);
    hipLaunchKernelGGL(vq_prep_b, dim3((K * D) / 1024), dim3(256), 0, stream, emb, Be);
    hipLaunchKernelGGL(vq_gemm, dim3(M / BMg, K / NCHUNK), dim3(256), 0, stream,
                       Ax, Be, e2g, gmin, cnt, list);
    hipLaunchKernelGGL(vq_rescore, dim3(M), dim3(64), 0, stream,
                       latents, emb, x2g, e2g, cnt, list, ids, ovfc, ovfl, best);
    hipLaunchKernelGGL(vq_fallback_par, dim3(2048), dim3(256), 0, stream,
                       latents, emb, x2g, e2g, ovfc, ovfl, best);
    hipLaunchKernelGGL(vq_finalize, dim3(64), dim3(256), 0, stream,
                       ovfc, ovfl, best, ids);
    hipLaunchKernelGGL(vq_gather, dim3(M / 64), dim3(256), 0, stream, emb, ids, out);
}